// Round 9
// baseline (152.042 us; speedup 1.0000x reference)
//
#include <hip/hip_runtime.h>
#include <hip/hip_bf16.h>
#include <math.h>

#define IN_F 128
#define OUT_F 64
#define BKT_SH 7          // 128 nodes per bucket
#define BKT_MASK 127
#define CHUNK 4096        // edges per partition block
#define MAXTB 1600        // max total buckets (2 * ceil(n/128)); n<=102k
#define IDX_BITS 25       // packed tmp: (local<<25)|idx ; needs n,E < 2^25
#define CAP 3072          // LDS edge capacity per bucket (avg 2048 here)

typedef __attribute__((ext_vector_type(8))) short bf16x8;
typedef __attribute__((ext_vector_type(4))) float f32x4;

__device__ inline short f2bf(float x) {
    __hip_bfloat16 b = __float2bfloat16(x);
    return *reinterpret_cast<short*>(&b);
}
__device__ inline float bflo(unsigned u) { return __uint_as_float(u << 16); }
__device__ inline float bfhi(unsigned u) { return __uint_as_float(u & 0xffff0000u); }

// ===================== fused: MFMA dual GEMM + bucket count =====================
__global__ __launch_bounds__(256) void k_fused(const float* __restrict__ h,
                                               const float* __restrict__ Wg,
                                               const float* __restrict__ Wc,
                                               const float* __restrict__ attn_l,
                                               const float* __restrict__ attn_r,
                                               __hip_bfloat16* __restrict__ feat,
                                               __hip_bfloat16* __restrict__ support,
                                               float* __restrict__ el,
                                               float* __restrict__ er, int n, int G1,
                                               const int* __restrict__ dst0,
                                               const int* __restrict__ row2,
                                               int* __restrict__ bcnt,
                                               int* __restrict__ chunkhist,
                                               int NB, int E_) {
    __shared__ short Wl[16][128][8];   // 32 KB
    __shared__ int hist[MAXTB];        // 6.4 KB

    if ((int)blockIdx.x >= G1) {
        // ---------- count part ----------
        int TB = 2 * NB;
        int t = threadIdx.x;
        int chunk = (int)blockIdx.x - G1;
        for (int i = t; i < TB; i += 256) hist[i] = 0;
        __syncthreads();
        int e0 = chunk * CHUNK;
        for (int i = t; i < CHUNK; i += 256) {
            int e = e0 + i;
            if (e < E_) {
                atomicAdd(&hist[dst0[e] >> BKT_SH], 1);
                atomicAdd(&hist[NB + (row2[e] >> BKT_SH)], 1);
            }
        }
        __syncthreads();
        int* hrow = chunkhist + (size_t)chunk * TB;
        for (int b = t; b < TB; b += 256) {
            int c = hist[b];
            hrow[b] = c;
            if (c) atomicAdd(&bcnt[b], c);
        }
        return;
    }

    // ---------- GEMM part ----------
    for (int i = threadIdx.x; i < 128 * 32; i += 256) {
        int k = i >> 5;
        int c4 = (i & 31) << 2;
        float4 v4 = (c4 < 64) ? *(const float4*)(Wg + k * 64 + c4)
                              : *(const float4*)(Wc + k * 64 + (c4 - 64));
        short* dst = &Wl[k >> 3][c4][k & 7];
        dst[0]  = f2bf(v4.x);
        dst[8]  = f2bf(v4.y);
        dst[16] = f2bf(v4.z);
        dst[24] = f2bf(v4.w);
    }
    __syncthreads();

    int lane = threadIdx.x & 63;
    int wv = threadIdx.x >> 6;
    int li = lane & 15, lg = lane >> 4;
    int row0 = blockIdx.x * 64 + wv * 16;

    f32x4 acc[8];
#pragma unroll
    for (int ct = 0; ct < 8; ++ct) acc[ct] = (f32x4){0.f, 0.f, 0.f, 0.f};

    int ar = row0 + li;
    if (ar >= n) ar = n - 1;
    const float* hrow = h + (size_t)ar * IN_F + lg * 8;
#pragma unroll
    for (int q = 0; q < 4; ++q) {
        float4 a0 = *(const float4*)(hrow + q * 32);
        float4 a1 = *(const float4*)(hrow + q * 32 + 4);
        bf16x8 af;
        af[0] = f2bf(a0.x); af[1] = f2bf(a0.y); af[2] = f2bf(a0.z); af[3] = f2bf(a0.w);
        af[4] = f2bf(a1.x); af[5] = f2bf(a1.y); af[6] = f2bf(a1.z); af[7] = f2bf(a1.w);
        int kg = q * 4 + lg;
#pragma unroll
        for (int ct = 0; ct < 8; ++ct) {
            bf16x8 bfr = *(const bf16x8*)&Wl[kg][ct * 16 + li][0];
            acc[ct] = __builtin_amdgcn_mfma_f32_16x16x32_bf16(af, bfr, acc[ct], 0, 0, 0);
        }
    }

    float alv[4], arv[4];
#pragma unroll
    for (int ct = 0; ct < 4; ++ct) {
        alv[ct] = attn_l[ct * 16 + li];
        arv[ct] = attn_r[ct * 16 + li];
    }
#pragma unroll
    for (int r = 0; r < 4; ++r) {
        int row = row0 + lg * 4 + r;
        float pl = 0.f, pr = 0.f;
#pragma unroll
        for (int ct = 0; ct < 4; ++ct) {
            pl += acc[ct][r] * alv[ct];
            pr += acc[ct][r] * arv[ct];
        }
#pragma unroll
        for (int m = 8; m; m >>= 1) {
            pl += __shfl_xor(pl, m);
            pr += __shfl_xor(pr, m);
        }
        if (li == 0 && row < n) { el[row] = pl; er[row] = pr; }
    }

#pragma unroll
    for (int r = 0; r < 4; ++r) {
        int row = row0 + lg * 4 + r;
        if (row >= n) continue;
#pragma unroll
        for (int ct = 0; ct < 4; ++ct)
            feat[(size_t)row * OUT_F + ct * 16 + li] = __float2bfloat16(acc[ct][r]);
#pragma unroll
        for (int ct = 4; ct < 8; ++ct)
            support[(size_t)row * OUT_F + (ct - 4) * 16 + li] = __float2bfloat16(acc[ct][r]);
    }
}

// ===================== scan bucket counts (1 block, single pass) ==============
__global__ __launch_bounds__(256) void k_bscan(const int* __restrict__ bcnt,
                                               int* __restrict__ boffs, int nb2,
                                               int grand) {
    __shared__ int sh[256];
    int t = threadIdx.x;
    int base = t * 8;
    int v[8];
    int sum = 0;
#pragma unroll
    for (int i = 0; i < 8; ++i) {
        int idx = base + i;
        v[i] = (idx < nb2) ? bcnt[idx] : 0;
        sum += v[i];
    }
    sh[t] = sum;
    __syncthreads();
    for (int off = 1; off < 256; off <<= 1) {
        int x = (t >= off) ? sh[t - off] : 0;
        __syncthreads();
        sh[t] += x;
        __syncthreads();
    }
    int run = sh[t] - sum;
#pragma unroll
    for (int i = 0; i < 8; ++i) {
        int idx = base + i;
        if (idx < nb2) boffs[idx] = run;
        run += v[i];
    }
    if (t == 0) boffs[nb2] = grand;
}

// ===================== partition: single edge pass, reuses chunk histograms ====
__global__ __launch_bounds__(256) void k_part(const int* __restrict__ src0,
                                              const int* __restrict__ dst0,
                                              const int* __restrict__ row2,
                                              const int* __restrict__ boffs,
                                              const int* __restrict__ chunkhist,
                                              int* __restrict__ gfill,
                                              unsigned* __restrict__ tmp, int NB, int E_) {
    __shared__ int hist[MAXTB];
    __shared__ int rbase[MAXTB];
    int TB = 2 * NB;
    int t = threadIdx.x;
    const int* hrow = chunkhist + (size_t)blockIdx.x * TB;
    for (int b = t; b < TB; b += 256) {
        int c = hrow[b];
        int bb = 0;
        if (c) bb = boffs[b] + atomicAdd(&gfill[b], c);
        rbase[b] = bb;
        hist[b] = 0;   // local fill counters
    }
    __syncthreads();
    int e0 = blockIdx.x * CHUNK;
    for (int i = t; i < CHUNK; i += 256) {
        int e = e0 + i;
        if (e < E_) {
            int d = dst0[e];
            int b = d >> BKT_SH;
            int p = atomicAdd(&hist[b], 1);
            tmp[(size_t)rbase[b] + p] =
                ((unsigned)(d & BKT_MASK) << IDX_BITS) | (unsigned)src0[e];
            int r = row2[e];
            int b2 = NB + (r >> BKT_SH);
            int p2 = atomicAdd(&hist[b2], 1);
            tmp[(size_t)rbase[b2] + p2] =
                ((unsigned)(r & BKT_MASK) << IDX_BITS) | (unsigned)e;
        }
    }
}

// ===================== fused per-bucket: build CSR in LDS + aggregate ==========
// One block per bucket. Build phase computes edge payload (idx, weight):
//   GAT: (src, exp(leaky(el[src]+er[dst])))   GC: (col2[eid], adj_val[eid])
// Aggregation: 8 half-waves x 16 nodes each; edges read from LDS (broadcast),
// only the feature-row gather goes to global.
__global__ __launch_bounds__(256) void k_bagg(const unsigned* __restrict__ tmp,
                                              const int* __restrict__ boffs,
                                              const float* __restrict__ el,
                                              const float* __restrict__ er,
                                              const __hip_bfloat16* __restrict__ feat,
                                              const __hip_bfloat16* __restrict__ support,
                                              const int* __restrict__ col2,
                                              const float* __restrict__ adj_val,
                                              const float* __restrict__ bias_gat,
                                              const float* __restrict__ bias_gc,
                                              int2* __restrict__ ewg,
                                              float* __restrict__ out, int NB, int n) {
    __shared__ int2 ew_lds[CAP + 1];
    __shared__ int hcnt[128], hoff[128], hfill[128], shs[128];
    __shared__ float er_lds[128];
    int b = blockIdx.x;
    int t = threadIdx.x;
    int base = boffs[b];
    int cnt = boffs[b + 1] - base;
    bool isGat = b < NB;
    int nodeBase = (isGat ? b : b - NB) << BKT_SH;

    if (t < 128) {
        hcnt[t] = 0;
        hfill[t] = 0;
        if (isGat && nodeBase + t < n) er_lds[t] = er[nodeBase + t];
    }
    __syncthreads();
    // histogram over local node ids
    for (int i = t; i < cnt; i += 256)
        atomicAdd(&hcnt[tmp[(size_t)base + i] >> IDX_BITS], 1);
    __syncthreads();
    if (t < 128) shs[t] = hcnt[t];
    __syncthreads();
    for (int off = 1; off < 128; off <<= 1) {
        int x = (t < 128 && t >= off) ? shs[t - off] : 0;
        __syncthreads();
        if (t < 128) shs[t] += x;
        __syncthreads();
    }
    if (t < 128) hoff[t] = shs[t] - hcnt[t];
    __syncthreads();

    int2* ews = (cnt <= CAP) ? (int2*)ew_lds : (ewg + base);
    // scatter + weight precompute (edge-parallel)
    for (int i = t; i < cnt; i += 256) {
        unsigned v = tmp[(size_t)base + i];
        unsigned loc = v >> IDX_BITS;
        int idx = (int)(v & ((1u << IDX_BITS) - 1u));
        int pdst = hoff[loc] + atomicAdd(&hfill[loc], 1);
        int2 payload;
        if (isGat) {
            float e = el[idx] + er_lds[loc];
            e = e > 0.f ? e : 0.2f * e;
            payload = make_int2(idx, __float_as_int(__expf(e)));  // no-max softmax
        } else {
            payload = make_int2(col2[idx], __float_as_int(adj_val[idx]));
        }
        ews[pdst] = payload;
    }
    __syncthreads();

    // ---------------- aggregation ----------------
    int hw = t >> 5;          // half-wave 0..7
    int ll = t & 31;
    int es2 = ll >> 4;        // edge slot 0/1
    int fg = ll & 15;         // feature group (uint2 = 4 feats)
    const uint2* fbase = (const uint2*)(isGat ? feat : support);
    const float* bias = isGat ? bias_gat : bias_gc;
    float4 bb = *(const float4*)(bias + fg * 4);
    int outoff = isGat ? 0 : OUT_F;

    for (int loc = hw; loc < 128; loc += 8) {
        int node = nodeBase + loc;
        if (node >= n) break;
        int start = hoff[loc], deg = hcnt[loc];
        float acc[4] = {0.f, 0.f, 0.f, 0.f};
        float sw = 0.f;
        for (int c0 = 0; c0 < deg; c0 += 32) {
            int c = min(32, deg - c0);
            if (isGat) {
                float w = (ll < c) ? __int_as_float(ews[start + c0 + ll].y) : 0.f;
                float ts = w;
                ts += __shfl_xor(ts, 1);  ts += __shfl_xor(ts, 2);
                ts += __shfl_xor(ts, 4);  ts += __shfl_xor(ts, 8);
                ts += __shfl_xor(ts, 16);
                sw += ts;
            }
#pragma unroll 4
            for (int k = 0; k < c; k += 2) {
                bool ok = (k + es2) < c;
                int ei = ok ? (start + c0 + k + es2) : start;
                int2 e = ews[ei];                       // LDS broadcast (16 lanes/addr)
                float wk = ok ? __int_as_float(e.y) : 0.f;
                uint2 pv = fbase[(size_t)e.x * 16 + fg];
                acc[0] += wk * bflo(pv.x); acc[1] += wk * bfhi(pv.x);
                acc[2] += wk * bflo(pv.y); acc[3] += wk * bfhi(pv.y);
            }
        }
#pragma unroll
        for (int j = 0; j < 4; ++j) acc[j] += __shfl_xor(acc[j], 16);
        if (es2 == 0) {
            float inv = isGat ? (deg > 0 ? __builtin_amdgcn_rcpf(sw) : 0.f) : 1.f;
            float z0 = acc[0] * inv + bb.x;
            float z1 = acc[1] * inv + bb.y;
            float z2 = acc[2] * inv + bb.z;
            float z3 = acc[3] * inv + bb.w;
            z0 = z0 > 0.f ? z0 : __expf(z0) - 1.f;
            z1 = z1 > 0.f ? z1 : __expf(z1) - 1.f;
            z2 = z2 > 0.f ? z2 : __expf(z2) - 1.f;
            z3 = z3 > 0.f ? z3 : __expf(z3) - 1.f;
            *(float4*)(out + (size_t)node * 128 + outoff + fg * 4) =
                make_float4(z0, z1, z2, z3);
        }
    }
}

// ===================== launch =====================
extern "C" void kernel_launch(void* const* d_in, const int* in_sizes, int n_in,
                              void* d_out, int out_size, void* d_ws, size_t ws_size,
                              hipStream_t stream) {
    const float* h        = (const float*)d_in[0];
    const int*   src0     = (const int*)d_in[1];
    const int*   dst0     = (const int*)d_in[2];
    const int*   row2     = (const int*)d_in[3];
    const int*   col2     = (const int*)d_in[4];
    const float* adj_val  = (const float*)d_in[5];
    const float* Wg       = (const float*)d_in[6];
    const float* attn_l   = (const float*)d_in[7];
    const float* attn_r   = (const float*)d_in[8];
    const float* bias_gat = (const float*)d_in[9];
    const float* Wc       = (const float*)d_in[10];
    const float* bias_gc  = (const float*)d_in[11];

    int n  = in_sizes[0] / IN_F;
    int E_ = in_sizes[1];
    float* out = (float*)d_out;

    int NB = (n + BKT_MASK) >> BKT_SH;
    int TB = 2 * NB;
    if (TB > MAXTB) return;
    if (n >= (1 << IDX_BITS) || E_ >= (1 << IDX_BITS)) return;

    int nchunk = (E_ + CHUNK - 1) / CHUNK;

    // ---- workspace layout with explicit alignment ----
    char* p = (char*)d_ws;
    auto alloc = [&](size_t bytes, size_t align) -> void* {
        size_t a = ((size_t)p + align - 1) & ~(align - 1);
        p = (char*)(a + bytes);
        return (void*)a;
    };
    unsigned* tmp = (unsigned*)alloc(2 * (size_t)E_ * sizeof(unsigned), 256);
    int2*  ewg   = (int2*) alloc((2 * (size_t)E_ + 1) * sizeof(int2), 256);
    float* el    = (float*)alloc((size_t)n * sizeof(float), 16);
    float* er    = (float*)alloc((size_t)n * sizeof(float), 16);
    int*   bcnt  = (int*)  alloc(2 * (size_t)TB * sizeof(int), 16);  // bcnt + gfill
    int*   gfill = bcnt + TB;
    int*   boffs = (int*)  alloc(((size_t)TB + 1) * sizeof(int), 16);
    int*   chunkhist = (int*)alloc((size_t)nchunk * TB * sizeof(int), 16);
    __hip_bfloat16* feat    = (__hip_bfloat16*)alloc((size_t)n * OUT_F * sizeof(__hip_bfloat16), 256);
    __hip_bfloat16* support = (__hip_bfloat16*)alloc((size_t)n * OUT_F * sizeof(__hip_bfloat16), 256);
    size_t need = (size_t)(p - (char*)d_ws);
    if (ws_size < need) return;

    int G1 = (n + 63) / 64;

    hipMemsetAsync(bcnt, 0, 2 * (size_t)TB * sizeof(int), stream);
    k_fused<<<G1 + nchunk, 256, 0, stream>>>(h, Wg, Wc, attn_l, attn_r,
                                             feat, support, el, er, n, G1,
                                             dst0, row2, bcnt, chunkhist, NB, E_);
    k_bscan<<<1, 256, 0, stream>>>(bcnt, boffs, TB, 2 * E_);
    k_part<<<nchunk, 256, 0, stream>>>(src0, dst0, row2, boffs, chunkhist,
                                       gfill, tmp, NB, E_);
    k_bagg<<<TB, 256, 0, stream>>>(tmp, boffs, el, er, feat, support,
                                   col2, adj_val, bias_gat, bias_gc,
                                   ewg, out, NB, n);
}

// Round 10
// 134.713 us; speedup vs baseline: 1.1286x; 1.1286x over previous
//
#include <hip/hip_runtime.h>
#include <hip/hip_bf16.h>
#include <math.h>

#define IN_F 128
#define OUT_F 64
#define BKT_SH 7          // 128 nodes per bucket
#define BKT_MASK 127
#define CHUNK 4096        // edges per partition block
#define MAXTB 1600        // max total buckets (2 * ceil(n/128)); n<=102k
#define IDX_BITS 25       // packed tmp: (local<<25)|idx ; needs n,E < 2^25

typedef __attribute__((ext_vector_type(8))) short bf16x8;
typedef __attribute__((ext_vector_type(4))) float f32x4;

__device__ inline short f2bf(float x) {
    __hip_bfloat16 b = __float2bfloat16(x);
    return *reinterpret_cast<short*>(&b);
}
__device__ inline float bflo(unsigned u) { return __uint_as_float(u << 16); }
__device__ inline float bfhi(unsigned u) { return __uint_as_float(u & 0xffff0000u); }

// ===================== fused: MFMA dual GEMM + bucket count =====================
__global__ __launch_bounds__(256) void k_fused(const float* __restrict__ h,
                                               const float* __restrict__ Wg,
                                               const float* __restrict__ Wc,
                                               const float* __restrict__ attn_l,
                                               const float* __restrict__ attn_r,
                                               __hip_bfloat16* __restrict__ feat,
                                               __hip_bfloat16* __restrict__ support,
                                               float* __restrict__ el,
                                               float* __restrict__ er, int n, int G1,
                                               const int* __restrict__ dst0,
                                               const int* __restrict__ row2,
                                               int* __restrict__ bcnt,
                                               int* __restrict__ chunkhist,
                                               int NB, int E_) {
    __shared__ short Wl[16][128][8];   // 32 KB
    __shared__ int hist[MAXTB];        // 6.4 KB

    if ((int)blockIdx.x >= G1) {
        // ---------- count part ----------
        int TB = 2 * NB;
        int t = threadIdx.x;
        int chunk = (int)blockIdx.x - G1;
        for (int i = t; i < TB; i += 256) hist[i] = 0;
        __syncthreads();
        int e0 = chunk * CHUNK;
        for (int i = t; i < CHUNK; i += 256) {
            int e = e0 + i;
            if (e < E_) {
                atomicAdd(&hist[dst0[e] >> BKT_SH], 1);
                atomicAdd(&hist[NB + (row2[e] >> BKT_SH)], 1);
            }
        }
        __syncthreads();
        int* hrow = chunkhist + (size_t)chunk * TB;
        for (int b = t; b < TB; b += 256) {
            int c = hist[b];
            hrow[b] = c;
            if (c) atomicAdd(&bcnt[b], c);
        }
        return;
    }

    // ---------- GEMM part ----------
    for (int i = threadIdx.x; i < 128 * 32; i += 256) {
        int k = i >> 5;
        int c4 = (i & 31) << 2;
        float4 v4 = (c4 < 64) ? *(const float4*)(Wg + k * 64 + c4)
                              : *(const float4*)(Wc + k * 64 + (c4 - 64));
        short* dst = &Wl[k >> 3][c4][k & 7];
        dst[0]  = f2bf(v4.x);
        dst[8]  = f2bf(v4.y);
        dst[16] = f2bf(v4.z);
        dst[24] = f2bf(v4.w);
    }
    __syncthreads();

    int lane = threadIdx.x & 63;
    int wv = threadIdx.x >> 6;
    int li = lane & 15, lg = lane >> 4;
    int row0 = blockIdx.x * 64 + wv * 16;

    f32x4 acc[8];
#pragma unroll
    for (int ct = 0; ct < 8; ++ct) acc[ct] = (f32x4){0.f, 0.f, 0.f, 0.f};

    int ar = row0 + li;
    if (ar >= n) ar = n - 1;
    const float* hrow = h + (size_t)ar * IN_F + lg * 8;
#pragma unroll
    for (int q = 0; q < 4; ++q) {
        float4 a0 = *(const float4*)(hrow + q * 32);
        float4 a1 = *(const float4*)(hrow + q * 32 + 4);
        bf16x8 af;
        af[0] = f2bf(a0.x); af[1] = f2bf(a0.y); af[2] = f2bf(a0.z); af[3] = f2bf(a0.w);
        af[4] = f2bf(a1.x); af[5] = f2bf(a1.y); af[6] = f2bf(a1.z); af[7] = f2bf(a1.w);
        int kg = q * 4 + lg;
#pragma unroll
        for (int ct = 0; ct < 8; ++ct) {
            bf16x8 bfr = *(const bf16x8*)&Wl[kg][ct * 16 + li][0];
            acc[ct] = __builtin_amdgcn_mfma_f32_16x16x32_bf16(af, bfr, acc[ct], 0, 0, 0);
        }
    }

    float alv[4], arv[4];
#pragma unroll
    for (int ct = 0; ct < 4; ++ct) {
        alv[ct] = attn_l[ct * 16 + li];
        arv[ct] = attn_r[ct * 16 + li];
    }
#pragma unroll
    for (int r = 0; r < 4; ++r) {
        int row = row0 + lg * 4 + r;
        float pl = 0.f, pr = 0.f;
#pragma unroll
        for (int ct = 0; ct < 4; ++ct) {
            pl += acc[ct][r] * alv[ct];
            pr += acc[ct][r] * arv[ct];
        }
#pragma unroll
        for (int m = 8; m; m >>= 1) {
            pl += __shfl_xor(pl, m);
            pr += __shfl_xor(pr, m);
        }
        if (li == 0 && row < n) { el[row] = pl; er[row] = pr; }
    }

#pragma unroll
    for (int r = 0; r < 4; ++r) {
        int row = row0 + lg * 4 + r;
        if (row >= n) continue;
#pragma unroll
        for (int ct = 0; ct < 4; ++ct)
            feat[(size_t)row * OUT_F + ct * 16 + li] = __float2bfloat16(acc[ct][r]);
#pragma unroll
        for (int ct = 4; ct < 8; ++ct)
            support[(size_t)row * OUT_F + (ct - 4) * 16 + li] = __float2bfloat16(acc[ct][r]);
    }
}

// ===================== scan bucket counts (1 block, single pass) ==============
__global__ __launch_bounds__(256) void k_bscan(const int* __restrict__ bcnt,
                                               int* __restrict__ boffs, int nb2,
                                               int grand, int* __restrict__ offs, int tot) {
    __shared__ int sh[256];
    int t = threadIdx.x;
    int base = t * 8;
    int v[8];
    int sum = 0;
#pragma unroll
    for (int i = 0; i < 8; ++i) {
        int idx = base + i;
        v[i] = (idx < nb2) ? bcnt[idx] : 0;
        sum += v[i];
    }
    sh[t] = sum;
    __syncthreads();
    for (int off = 1; off < 256; off <<= 1) {
        int x = (t >= off) ? sh[t - off] : 0;
        __syncthreads();
        sh[t] += x;
        __syncthreads();
    }
    int run = sh[t] - sum;
#pragma unroll
    for (int i = 0; i < 8; ++i) {
        int idx = base + i;
        if (idx < nb2) boffs[idx] = run;
        run += v[i];
    }
    if (t == 0) { boffs[nb2] = grand; offs[tot] = grand; }
}

// ===================== partition: single edge pass, reuses chunk histograms ====
__global__ __launch_bounds__(256) void k_part(const int* __restrict__ src0,
                                              const int* __restrict__ dst0,
                                              const int* __restrict__ row2,
                                              const int* __restrict__ boffs,
                                              const int* __restrict__ chunkhist,
                                              int* __restrict__ gfill,
                                              unsigned* __restrict__ tmp, int NB, int E_) {
    __shared__ int hist[MAXTB];
    __shared__ int rbase[MAXTB];
    int TB = 2 * NB;
    int t = threadIdx.x;
    const int* hrow = chunkhist + (size_t)blockIdx.x * TB;
    for (int b = t; b < TB; b += 256) {
        int c = hrow[b];
        int bb = 0;
        if (c) bb = boffs[b] + atomicAdd(&gfill[b], c);
        rbase[b] = bb;
        hist[b] = 0;   // local fill counters
    }
    __syncthreads();
    int e0 = blockIdx.x * CHUNK;
    for (int i = t; i < CHUNK; i += 256) {
        int e = e0 + i;
        if (e < E_) {
            int d = dst0[e];
            int b = d >> BKT_SH;
            int p = atomicAdd(&hist[b], 1);
            tmp[(size_t)rbase[b] + p] =
                ((unsigned)(d & BKT_MASK) << IDX_BITS) | (unsigned)src0[e];
            int r = row2[e];
            int b2 = NB + (r >> BKT_SH);
            int p2 = atomicAdd(&hist[b2], 1);
            tmp[(size_t)rbase[b2] + p2] =
                ((unsigned)(r & BKT_MASK) << IDX_BITS) | (unsigned)e;
        }
    }
}

// ===================== build fine CSR + edge weights (edge-parallel) ==========
// Emits ew[pos] = (feature_row_idx, weight):
//   GAT bucket: (src, exp(leaky(el[src] + er[dst])))    [no-max softmax]
//   GC  bucket: (col2[eid], adj_val[eid])
__global__ __launch_bounds__(256) void k_bbuild(const unsigned* __restrict__ tmp,
                                                const int* __restrict__ boffs,
                                                const float* __restrict__ el,
                                                const float* __restrict__ er,
                                                const int* __restrict__ col2,
                                                const float* __restrict__ adj_val,
                                                int* __restrict__ offs,
                                                int2* __restrict__ ew, int NB, int n) {
    __shared__ int hcnt[128], hoff[128], hfill[128], sh[128];
    __shared__ float er_lds[128];
    int b = blockIdx.x;
    int t = threadIdx.x;
    int base = boffs[b];
    int cnt = boffs[b + 1] - base;
    bool isGat = b < NB;
    int nodeBase = (isGat ? b : b - NB) << BKT_SH;
    int offsBase = (isGat ? 0 : n) + nodeBase;

    if (t < 128) {
        hcnt[t] = 0;
        hfill[t] = 0;
        if (isGat && nodeBase + t < n) er_lds[t] = er[nodeBase + t];
    }
    __syncthreads();
    for (int i = t; i < cnt; i += 256)
        atomicAdd(&hcnt[tmp[(size_t)base + i] >> IDX_BITS], 1);
    __syncthreads();
    if (t < 128) sh[t] = hcnt[t];
    __syncthreads();
    for (int off = 1; off < 128; off <<= 1) {
        int x = (t < 128 && t >= off) ? sh[t - off] : 0;
        __syncthreads();
        if (t < 128) sh[t] += x;
        __syncthreads();
    }
    if (t < 128) {
        hoff[t] = sh[t] - hcnt[t];
        if (nodeBase + t < n) offs[offsBase + t] = base + hoff[t];
    }
    __syncthreads();
    for (int i = t; i < cnt; i += 256) {
        unsigned v = tmp[(size_t)base + i];
        unsigned loc = v >> IDX_BITS;
        int idx = (int)(v & ((1u << IDX_BITS) - 1u));
        int2 payload;
        if (isGat) {
            float e = el[idx] + er_lds[loc];
            e = e > 0.f ? e : 0.2f * e;
            payload = make_int2(idx, __float_as_int(__expf(e)));
        } else {
            payload = make_int2(col2[idx], __float_as_int(adj_val[idx]));
        }
        int p = atomicAdd(&hfill[loc], 1);
        ew[(size_t)base + hoff[loc] + p] = payload;
    }
}

// ===================== aggregation: 2 nodes per wave, unified =====================
// Half-wave (32 lanes) per node: 2 edge slots x 16 feature lanes (uint2 = 4 feats).
// Waves [0, nh): GAT pairs; waves [nh, 2nh): GC pairs. nh = ceil(n/2).
// Per-node chain is offs -> ew -> feature row (2 memory levels, no exp).
__global__ __launch_bounds__(256) void k_agg(const int2* __restrict__ ew,
                                             const int* __restrict__ offs,
                                             const __hip_bfloat16* __restrict__ feat,
                                             const __hip_bfloat16* __restrict__ support,
                                             const float* __restrict__ bias_gat,
                                             const float* __restrict__ bias_gc,
                                             float* __restrict__ out, int n) {
    int wave = (int)(((long long)blockIdx.x * blockDim.x + threadIdx.x) >> 6);
    int lane = threadIdx.x & 63;
    int nh = (n + 1) >> 1;
    if (wave >= 2 * nh) return;
    int half = lane >> 5;     // node within pair
    int ll = lane & 31;       // lane within half
    int es2 = ll >> 4;        // edge slot (0/1)
    int fg = ll & 15;         // feature group (4 feats, uint2)
    int sbase = half << 5;

    bool isGat = wave < nh;
    int node = (isGat ? wave : wave - nh) * 2 + half;
    bool nodeValid = node < n;
    int wid = (isGat ? 0 : n) + (nodeValid ? node : 0);
    int start = offs[wid];
    int deg = nodeValid ? offs[wid + 1] - start : 0;

    const uint2* fbase = (const uint2*)(isGat ? feat : support);  // row = 16 uint2
    float acc[4] = {0.f, 0.f, 0.f, 0.f};
    float sw = 0.f;

    for (int c0 = 0; c0 < deg; c0 += 32) {
        int cnt = min(32, deg - c0);
        bool valid = ll < cnt;
        int2 e = valid ? ew[(size_t)start + c0 + ll] : make_int2(0, 0);
        float w = __int_as_float(e.y);       // 0.0f when invalid
        float ts = w;
        ts += __shfl_xor(ts, 1);  ts += __shfl_xor(ts, 2);
        ts += __shfl_xor(ts, 4);  ts += __shfl_xor(ts, 8);
        ts += __shfl_xor(ts, 16);
        sw += ts;
#pragma unroll 4
        for (int k = 0; k < cnt; k += 2) {
            int src = sbase + k + es2;
            float wk = __shfl(w, src);       // zero beyond cnt
            int ik = __shfl(e.x, src);
            uint2 pv = fbase[(size_t)ik * 16 + fg];
            acc[0] += wk * bflo(pv.x); acc[1] += wk * bfhi(pv.x);
            acc[2] += wk * bflo(pv.y); acc[3] += wk * bfhi(pv.y);
        }
    }
#pragma unroll
    for (int j = 0; j < 4; ++j) acc[j] += __shfl_xor(acc[j], 16);
    if (es2 == 0 && nodeValid) {
        float inv = isGat ? (deg > 0 ? __builtin_amdgcn_rcpf(sw) : 0.f) : 1.f;
        const float* bias = isGat ? bias_gat : bias_gc;
        int outoff = isGat ? 0 : OUT_F;
        float4 bb = *(const float4*)(bias + fg * 4);
        float z0 = acc[0] * inv + bb.x;
        float z1 = acc[1] * inv + bb.y;
        float z2 = acc[2] * inv + bb.z;
        float z3 = acc[3] * inv + bb.w;
        z0 = z0 > 0.f ? z0 : __expf(z0) - 1.f;
        z1 = z1 > 0.f ? z1 : __expf(z1) - 1.f;
        z2 = z2 > 0.f ? z2 : __expf(z2) - 1.f;
        z3 = z3 > 0.f ? z3 : __expf(z3) - 1.f;
        *(float4*)(out + (size_t)node * 128 + outoff + fg * 4) = make_float4(z0, z1, z2, z3);
    }
}

// ===================== launch =====================
extern "C" void kernel_launch(void* const* d_in, const int* in_sizes, int n_in,
                              void* d_out, int out_size, void* d_ws, size_t ws_size,
                              hipStream_t stream) {
    const float* h        = (const float*)d_in[0];
    const int*   src0     = (const int*)d_in[1];
    const int*   dst0     = (const int*)d_in[2];
    const int*   row2     = (const int*)d_in[3];
    const int*   col2     = (const int*)d_in[4];
    const float* adj_val  = (const float*)d_in[5];
    const float* Wg       = (const float*)d_in[6];
    const float* attn_l   = (const float*)d_in[7];
    const float* attn_r   = (const float*)d_in[8];
    const float* bias_gat = (const float*)d_in[9];
    const float* Wc       = (const float*)d_in[10];
    const float* bias_gc  = (const float*)d_in[11];

    int n  = in_sizes[0] / IN_F;
    int E_ = in_sizes[1];
    float* out = (float*)d_out;

    int NB = (n + BKT_MASK) >> BKT_SH;
    int TB = 2 * NB;
    if (TB > MAXTB) return;
    if (n >= (1 << IDX_BITS) || E_ >= (1 << IDX_BITS)) return;

    int nchunk = (E_ + CHUNK - 1) / CHUNK;

    // ---- workspace layout with explicit alignment ----
    char* p = (char*)d_ws;
    auto alloc = [&](size_t bytes, size_t align) -> void* {
        size_t a = ((size_t)p + align - 1) & ~(align - 1);
        p = (char*)(a + bytes);
        return (void*)a;
    };
    unsigned* tmp = (unsigned*)alloc(2 * (size_t)E_ * sizeof(unsigned), 256);
    int2*  ew    = (int2*) alloc(2 * (size_t)E_ * sizeof(int2), 256);
    int*   offs  = (int*)  alloc((2 * (size_t)n + 1) * sizeof(int), 16);
    float* el    = (float*)alloc((size_t)n * sizeof(float), 16);
    float* er    = (float*)alloc((size_t)n * sizeof(float), 16);
    int*   bcnt  = (int*)  alloc(2 * (size_t)TB * sizeof(int), 16);  // bcnt + gfill
    int*   gfill = bcnt + TB;
    int*   boffs = (int*)  alloc(((size_t)TB + 1) * sizeof(int), 16);
    int*   chunkhist = (int*)alloc((size_t)nchunk * TB * sizeof(int), 16);
    __hip_bfloat16* feat    = (__hip_bfloat16*)alloc((size_t)n * OUT_F * sizeof(__hip_bfloat16), 256);
    __hip_bfloat16* support = (__hip_bfloat16*)alloc((size_t)n * OUT_F * sizeof(__hip_bfloat16), 256);
    size_t need = (size_t)(p - (char*)d_ws);
    if (ws_size < need) return;

    int G1 = (n + 63) / 64;

    hipMemsetAsync(bcnt, 0, 2 * (size_t)TB * sizeof(int), stream);
    k_fused<<<G1 + nchunk, 256, 0, stream>>>(h, Wg, Wc, attn_l, attn_r,
                                             feat, support, el, er, n, G1,
                                             dst0, row2, bcnt, chunkhist, NB, E_);
    k_bscan<<<1, 256, 0, stream>>>(bcnt, boffs, TB, 2 * E_, offs, 2 * n);
    k_part<<<nchunk, 256, 0, stream>>>(src0, dst0, row2, boffs, chunkhist,
                                       gfill, tmp, NB, E_);
    k_bbuild<<<TB, 256, 0, stream>>>(tmp, boffs, el, er, col2, adj_val,
                                     offs, ew, NB, n);
    int nh = (n + 1) >> 1;
    long long aggthreads = 2LL * nh * 64;
    k_agg<<<(int)((aggthreads + 255) / 256), 256, 0, stream>>>(
        ew, offs, feat, support, bias_gat, bias_gc, out, n);
}